// Round 12
// baseline (122.360 us; speedup 1.0000x reference)
//
#include <hip/hip_runtime.h>
#include <hip/hip_bf16.h>
#include <cstdint>
#include <cstddef>

#define BATCH 16
#define NROWS 4096
#define MROWS 2048
#define DDIM  256
#define NSPLIT 2
#define NCHUNKS 8            // (NROWS/NSPLIT)/256

typedef __attribute__((ext_vector_type(8))) short short8;
typedef __attribute__((ext_vector_type(4))) float f32x4;

static __device__ __forceinline__ unsigned short f2bf(float f) {
  unsigned int x = __float_as_uint(f);
  x += 0x7fffu + ((x >> 16) & 1u);
  return (unsigned short)(x >> 16);
}

// ---------------- Kernel 1: row L2-normalize + bf16 cast ----------------
__global__ void __launch_bounds__(256) norm_cast(
    const float* __restrict__ x1, const float* __restrict__ x2,
    unsigned short* __restrict__ aout, unsigned short* __restrict__ bout) {
  const int wid  = threadIdx.x >> 6;
  const int lane = threadIdx.x & 63;
  const long long row = (long long)blockIdx.x * 4 + wid;
  const long long R1 = (long long)BATCH * NROWS;
  const long long R2 = (long long)BATCH * MROWS;
  if (row >= R1 + R2) return;
  const float* src; unsigned short* dst;
  if (row < R1) { src = x1 + row * DDIM; dst = aout + row * DDIM; }
  else { long long r2 = row - R1; src = x2 + r2 * DDIM; dst = bout + r2 * DDIM; }
  float4 v = ((const float4*)src)[lane];
  float ss = v.x*v.x + v.y*v.y + v.z*v.z + v.w*v.w;
  #pragma unroll
  for (int o = 32; o >= 1; o >>= 1) ss += __shfl_xor(ss, o, 64);
  float n = sqrtf(ss);
  float sc = 1.0f / fmaxf(n, 1e-12f);
  ushort4 o;
  o.x = f2bf(v.x * sc); o.y = f2bf(v.y * sc);
  o.z = f2bf(v.z * sc); o.w = f2bf(v.w * sc);
  ((ushort4*)dst)[lane] = o;
}

// ---------------- Kernel 2: 8-phase 256x256 fused GEMM + column-max + loss ----------------
typedef __attribute__((address_space(1))) const void gas_t;
typedef __attribute__((address_space(3))) void las_t;
#define GLL16(g, l) __builtin_amdgcn_global_load_lds((gas_t*)(g), (las_t*)(l), 16, 0, 0)

// LDS slots: [256 rows][32 k] bf16 = 16 KB each. A: parity x ks, then B.
#define LDSA(P,K) (lds + (((P)*2+(K))<<14))
#define LDSB(P,K) (lds + 65536 + (((P)*2+(K))<<14))

static __device__ __forceinline__ short8 ldsfrag(const char* slot, int row, int pslot) {
  return *(const short8*)(slot + row * 64 + (pslot << 4));
}

__global__ void __launch_bounds__(512, 1) maxsim_gemm8(
    const unsigned short* __restrict__ A,   // [BATCH][NROWS][DDIM]
    const unsigned short* __restrict__ Bm,  // [BATCH][MROWS][DDIM]
    float* __restrict__ partials,           // [NSPLIT][BATCH][MROWS]
    const float* __restrict__ y,
    float* __restrict__ out,                // scalar loss (pre-zeroed)
    unsigned* __restrict__ bcnt)            // [BATCH] arrival counters (pre-zeroed)
{
  __shared__ __align__(16) char lds[131072];

  const int t = threadIdx.x;
  const int lane = t & 63;
  const int w = t >> 6;
  const int wr = w >> 2;     // n-half (wave owns 128 rows)
  const int wc = w & 3;      // m-quarter (wave owns 64 cols)
  const int lrow = lane & 15;
  const int pslot = (lane >> 4) ^ ((lane >> 1) & 3);  // swizzled 16B slot for frag reads

  // XCD-aware bijective swizzle: 256 blocks, XCD k owns batches {2k,2k+1}
  // (=> all 16 blocks of a batch share one XCD/L2; cheap last-block reduce).
  const int hw = blockIdx.x;
  const int logical = (hw & 7) * 32 + (hw >> 3);
  const int mt = logical & 7;
  const int grp = logical >> 3;
  const int sp = grp & 1;
  const int bb = grp >> 1;

  const int m0 = mt * 256;
  const int nbase = sp * (NROWS / NSPLIT);

  const unsigned short* Aba = A  + (size_t)bb * NROWS * DDIM;
  const unsigned short* Bba = Bm + ((size_t)bb * MROWS + m0) * DDIM;

  // Per-thread staging bases (hoisted): chunk c = w*2+i covers rows c*16..+15.
  // Source k-slot pre-swizzled: sphys = (lane&3) ^ ((lane>>3)&3).
  const int r0 = (w * 2 + 0) * 16 + (lane >> 2);
  const int r1 = (w * 2 + 1) * 16 + (lane >> 2);
  const int sph8 = (((lane & 3) ^ ((lane >> 3) & 3)) << 3);
  const unsigned short* sA0 = Aba + (size_t)r0 * DDIM + sph8;
  const unsigned short* sA1 = Aba + (size_t)r1 * DDIM + sph8;
  const unsigned short* sB0 = Bba + (size_t)r0 * DDIM + sph8;
  const unsigned short* sB1 = Bba + (size_t)r1 * DDIM + sph8;
  const int l0 = (w * 2 + 0) * 1024 + lane * 16;   // slot-relative LDS dest
  const int l1 = (w * 2 + 1) * 1024 + lane * 16;

  #define STAGE_A(SLOT, OFF) do { \
    GLL16(sA0 + (OFF), (SLOT) + l0); GLL16(sA1 + (OFF), (SLOT) + l1); } while (0)
  #define STAGE_B(SLOT, OFF) do { \
    GLL16(sB0 + (OFF), (SLOT) + l0); GLL16(sB1 + (OFF), (SLOT) + l1); } while (0)

  f32x4 acc[8][4] = {};
  short8 afr[4], bfr[4];
  float cm[4] = {-INFINITY, -INFINITY, -INFINITY, -INFINITY};

  // ---- Prologue: tile0 (4 halves) + tile1's {B ks0, A ks0, B ks1}.
  STAGE_A(LDSA(0,0), nbase * DDIM + 0);
  STAGE_B(LDSB(0,0), 0);
  STAGE_A(LDSA(0,1), nbase * DDIM + 32);
  STAGE_B(LDSB(0,1), 32);
  STAGE_B(LDSB(1,0), 64);
  STAGE_A(LDSA(1,0), nbase * DDIM + 64);
  STAGE_B(LDSB(1,1), 96);
  asm volatile("s_waitcnt vmcnt(6)" ::: "memory");   // tile0 fully landed
  asm volatile("s_barrier" ::: "memory");

  // Phase: [optional B-read] + 4 A-reads; stage 1 half; lgkm; barrier; 16 MFMA; barrier.
  // No setprio (R11 A/B: removal = +4% on this lockstep schedule, cf. m190).
  #define PHASE(RDB, BSLOT, ASLOT, MIOFF, STAGE_STMT, VMW) do {                    \
    if (RDB) {                                                                     \
      _Pragma("unroll")                                                            \
      for (int nj = 0; nj < 4; ++nj)                                               \
        bfr[nj] = ldsfrag(BSLOT, wc*64 + nj*16 + lrow, pslot);                     \
    }                                                                              \
    _Pragma("unroll")                                                              \
    for (int mi = 0; mi < 4; ++mi)                                                 \
      afr[mi] = ldsfrag(ASLOT, wr*128 + ((MIOFF)+mi)*16 + lrow, pslot);            \
    STAGE_STMT;                                                                    \
    asm volatile("s_waitcnt lgkmcnt(0)" ::: "memory");                             \
    asm volatile("s_barrier" ::: "memory");                                        \
    _Pragma("unroll")                                                              \
    for (int mi = 0; mi < 4; ++mi)                                                 \
      _Pragma("unroll")                                                            \
      for (int nj = 0; nj < 4; ++nj)                                               \
        acc[(MIOFF)+mi][nj] = __builtin_amdgcn_mfma_f32_16x16x32_bf16(             \
            afr[mi], bfr[nj], acc[(MIOFF)+mi][nj], 0, 0, 0);                       \
    if (VMW) asm volatile("s_waitcnt vmcnt(6)" ::: "memory");                      \
    asm volatile("s_barrier" ::: "memory");                                        \
  } while (0)

  for (int nc = 0; nc < NCHUNKS; ++nc) {
    #pragma unroll
    for (int kt = 0; kt < 4; ++kt) {
      const int par  = kt & 1;
      const int npar = par ^ 1;
      // Stage ledger: ph0 completes tile T+1 (A ks1); ph1-3 issue tile T+2's
      // {B ks0, A ks0, B ks1}. vmcnt(6) at ph3 => tile T+1 fully landed.
      const int ncA1 = (kt < 3) ? nc : ((nc + 1) & (NCHUNKS - 1));  // T+1's chunk
      const int kA1  = ((kt + 1) & 3) * 64 + 32;
      const int ncT2 = (kt < 2) ? nc : ((nc + 1) & (NCHUNKS - 1));  // T+2's chunk
      const int kT2  = ((kt + 2) & 3) * 64;
      const int offA1 = (nbase + ncA1 * 256) * DDIM + kA1;
      const int offA2 = (nbase + ncT2 * 256) * DDIM + kT2;

      PHASE(1, LDSB(par,0), LDSA(par,0), 0, STAGE_A(LDSA(npar,1), offA1), 0);
      PHASE(0, LDSB(par,0), LDSA(par,0), 4, STAGE_B(LDSB(par,0), kT2),    0);
      PHASE(1, LDSB(par,1), LDSA(par,1), 0, STAGE_A(LDSA(par,0), offA2),  0);
      PHASE(0, LDSB(par,1), LDSA(par,1), 4, STAGE_B(LDSB(par,1), kT2+32), 1);
    }
    // fold this n-chunk's C tile into running column max; reset acc
    #pragma unroll
    for (int nj = 0; nj < 4; ++nj) {
      float v = cm[nj];
      #pragma unroll
      for (int mi = 0; mi < 8; ++mi) {
        v = fmaxf(fmaxf(fmaxf(fmaxf(v, acc[mi][nj][0]), acc[mi][nj][1]),
                        acc[mi][nj][2]), acc[mi][nj][3]);
        acc[mi][nj] = (f32x4){0.0f, 0.0f, 0.0f, 0.0f};
      }
      cm[nj] = v;
    }
  }
  #undef PHASE

  // ---- Epilogue: drain DMA, reduce max across lanes/waves, write partials
  asm volatile("s_waitcnt vmcnt(0)" ::: "memory");
  asm volatile("s_barrier" ::: "memory");
  float* cmax = (float*)lds;   // [2][256]
  #pragma unroll
  for (int nj = 0; nj < 4; ++nj) {
    cm[nj] = fmaxf(cm[nj], __shfl_xor(cm[nj], 16, 64));
    cm[nj] = fmaxf(cm[nj], __shfl_xor(cm[nj], 32, 64));
  }
  if (lane < 16) {
    #pragma unroll
    for (int nj = 0; nj < 4; ++nj)
      cmax[wr * 256 + wc * 64 + nj * 16 + lane] = cm[nj];
  }
  __syncthreads();
  if (t < 256) {
    float v = fmaxf(cmax[t], cmax[256 + t]);
    partials[((size_t)sp * BATCH + bb) * MROWS + m0 + t] = v;
  }

  // ---- Fold tail: last-arriving block of each batch computes the loss term.
  __threadfence();             // publish partials (release)
  __syncthreads();             // all threads' stores+fences done before t0 signals
  __shared__ unsigned amlast_s;
  if (t == 0) amlast_s = (atomicAdd(&bcnt[bb], 1u) == 15u) ? 1u : 0u;
  __syncthreads();
  if (amlast_s) {
    __threadfence();           // acquire: other blocks' partials now visible
    float s = 0.0f;
    for (int m = t; m < MROWS; m += 512) {
      float v = fmaxf(partials[(size_t)bb * MROWS + m],
                      partials[((size_t)BATCH + bb) * MROWS + m]);
      s += v;
    }
    #pragma unroll
    for (int o = 32; o >= 1; o >>= 1) s += __shfl_xor(s, o, 64);
    float* red = (float*)(lds + 4096);
    if (lane == 0) red[w] = s;
    __syncthreads();
    if (t == 0) {
      float tot = 0.0f;
      #pragma unroll
      for (int i = 0; i < 8; ++i) tot += red[i];
      float mean = tot / (float)MROWS;
      float d = mean - y[bb];
      atomicAdd(out, d * d);   // Y_SCALE == 1.0
    }
  }
}

extern "C" void kernel_launch(void* const* d_in, const int* in_sizes, int n_in,
                              void* d_out, int out_size, void* d_ws, size_t ws_size,
                              hipStream_t stream) {
  const float* x1 = (const float*)d_in[0];
  const float* x2 = (const float*)d_in[1];
  const float* y  = (const float*)d_in[2];
  float* out = (float*)d_out;

  unsigned short* aBF = (unsigned short*)d_ws;
  unsigned short* bBF = aBF + (size_t)BATCH * NROWS * DDIM;
  float* partials = (float*)(bBF + (size_t)BATCH * MROWS * DDIM);
  unsigned* bcnt = (unsigned*)(partials + (size_t)NSPLIT * BATCH * MROWS);

  // Zero the arrival counters and the output accumulator every launch
  // (ws/out are poisoned 0xAA once and never re-poisoned between replays).
  hipMemsetAsync(bcnt, 0, BATCH * sizeof(unsigned), stream);
  hipMemsetAsync(out, 0, sizeof(float), stream);

  const int totRows = BATCH * (NROWS + MROWS);
  norm_cast<<<(totRows + 3) / 4, 256, 0, stream>>>(x1, x2, aBF, bBF);
  maxsim_gemm8<<<BATCH * 8 * NSPLIT, 512, 0, stream>>>(aBF, bBF, partials, y, out, bcnt);
}

// Round 13
// 85.948 us; speedup vs baseline: 1.4237x; 1.4237x over previous
//
#include <hip/hip_runtime.h>
#include <hip/hip_bf16.h>
#include <cstdint>
#include <cstddef>

#define BATCH 16
#define NROWS 4096
#define MROWS 2048
#define DDIM  256
#define NSPLIT 2
#define NCHUNKS 8            // (NROWS/NSPLIT)/256

typedef __attribute__((ext_vector_type(8))) short short8;
typedef __attribute__((ext_vector_type(4))) float f32x4;

static __device__ __forceinline__ unsigned short f2bf(float f) {
  unsigned int x = __float_as_uint(f);
  x += 0x7fffu + ((x >> 16) & 1u);
  return (unsigned short)(x >> 16);
}

// ---------------- Kernel 1: row L2-normalize + bf16 cast ----------------
__global__ void __launch_bounds__(256) norm_cast(
    const float* __restrict__ x1, const float* __restrict__ x2,
    unsigned short* __restrict__ aout, unsigned short* __restrict__ bout) {
  const int wid  = threadIdx.x >> 6;
  const int lane = threadIdx.x & 63;
  const long long row = (long long)blockIdx.x * 4 + wid;
  const long long R1 = (long long)BATCH * NROWS;
  const long long R2 = (long long)BATCH * MROWS;
  if (row >= R1 + R2) return;
  const float* src; unsigned short* dst;
  if (row < R1) { src = x1 + row * DDIM; dst = aout + row * DDIM; }
  else { long long r2 = row - R1; src = x2 + r2 * DDIM; dst = bout + r2 * DDIM; }
  float4 v = ((const float4*)src)[lane];
  float ss = v.x*v.x + v.y*v.y + v.z*v.z + v.w*v.w;
  #pragma unroll
  for (int o = 32; o >= 1; o >>= 1) ss += __shfl_xor(ss, o, 64);
  float n = sqrtf(ss);
  float sc = 1.0f / fmaxf(n, 1e-12f);
  ushort4 o;
  o.x = f2bf(v.x * sc); o.y = f2bf(v.y * sc);
  o.z = f2bf(v.z * sc); o.w = f2bf(v.w * sc);
  ((ushort4*)dst)[lane] = o;
}

// ---------------- Kernel 2: 8-phase 256x256 fused GEMM + column-max ----------------
typedef __attribute__((address_space(1))) const void gas_t;
typedef __attribute__((address_space(3))) void las_t;
#define GLL16(g, l) __builtin_amdgcn_global_load_lds((gas_t*)(g), (las_t*)(l), 16, 0, 0)

// LDS slots: [256 rows][32 k] bf16 = 16 KB each. A: parity x ks, then B.
#define LDSA(P,K) (lds + (((P)*2+(K))<<14))
#define LDSB(P,K) (lds + 65536 + (((P)*2+(K))<<14))

static __device__ __forceinline__ short8 ldsfrag(const char* slot, int row, int pslot) {
  return *(const short8*)(slot + row * 64 + (pslot << 4));
}

__global__ void __launch_bounds__(512, 1) maxsim_gemm8(
    const unsigned short* __restrict__ A,   // [BATCH][NROWS][DDIM]
    const unsigned short* __restrict__ Bm,  // [BATCH][MROWS][DDIM]
    float* __restrict__ partials)           // [NSPLIT][BATCH][MROWS]
{
  __shared__ __align__(16) char lds[131072];

  const int t = threadIdx.x;
  const int lane = t & 63;
  const int w = t >> 6;
  const int wr = w >> 2;     // n-half (wave owns 128 rows)
  const int wc = w & 3;      // m-quarter (wave owns 64 cols)
  const int lrow = lane & 15;
  const int pslot = (lane >> 4) ^ ((lane >> 1) & 3);  // swizzled 16B slot for frag reads

  // XCD-aware bijective swizzle: 256 blocks, XCD k owns batches {2k,2k+1}.
  const int hw = blockIdx.x;
  const int logical = (hw & 7) * 32 + (hw >> 3);
  const int mt = logical & 7;
  const int grp = logical >> 3;
  const int sp = grp & 1;
  const int bb = grp >> 1;

  const int m0 = mt * 256;
  const int nbase = sp * (NROWS / NSPLIT);

  const unsigned short* Aba = A  + (size_t)bb * NROWS * DDIM;
  const unsigned short* Bba = Bm + ((size_t)bb * MROWS + m0) * DDIM;

  // Per-thread staging bases (hoisted): chunk c = w*2+i covers rows c*16..+15.
  // Source k-slot pre-swizzled: sphys = (lane&3) ^ ((lane>>3)&3).
  const int r0 = (w * 2 + 0) * 16 + (lane >> 2);
  const int r1 = (w * 2 + 1) * 16 + (lane >> 2);
  const int sph8 = (((lane & 3) ^ ((lane >> 3) & 3)) << 3);
  const unsigned short* sA0 = Aba + (size_t)r0 * DDIM + sph8;
  const unsigned short* sA1 = Aba + (size_t)r1 * DDIM + sph8;
  const unsigned short* sB0 = Bba + (size_t)r0 * DDIM + sph8;
  const unsigned short* sB1 = Bba + (size_t)r1 * DDIM + sph8;
  const int l0 = (w * 2 + 0) * 1024 + lane * 16;   // slot-relative LDS dest
  const int l1 = (w * 2 + 1) * 1024 + lane * 16;

  #define STAGE_A(SLOT, OFF) do { \
    GLL16(sA0 + (OFF), (SLOT) + l0); GLL16(sA1 + (OFF), (SLOT) + l1); } while (0)
  #define STAGE_B(SLOT, OFF) do { \
    GLL16(sB0 + (OFF), (SLOT) + l0); GLL16(sB1 + (OFF), (SLOT) + l1); } while (0)

  f32x4 acc[8][4] = {};
  short8 afr[4], bfr[4];
  float cm[4] = {-INFINITY, -INFINITY, -INFINITY, -INFINITY};

  // ---- Prologue: tile0 (4 halves) + tile1's {B ks0, A ks0, B ks1}.
  STAGE_A(LDSA(0,0), nbase * DDIM + 0);
  STAGE_B(LDSB(0,0), 0);
  STAGE_A(LDSA(0,1), nbase * DDIM + 32);
  STAGE_B(LDSB(0,1), 32);
  STAGE_B(LDSB(1,0), 64);
  STAGE_A(LDSA(1,0), nbase * DDIM + 64);
  STAGE_B(LDSB(1,1), 96);
  asm volatile("s_waitcnt vmcnt(6)" ::: "memory");   // tile0 fully landed
  asm volatile("s_barrier" ::: "memory");

  // Phase: [optional B-read] + 4 A-reads; stage 1 half; lgkm; barrier; 16 MFMA; barrier.
  // No setprio (R11 A/B: removal = +4% on this lockstep schedule, cf. m190).
  #define PHASE(RDB, BSLOT, ASLOT, MIOFF, STAGE_STMT, VMW) do {                    \
    if (RDB) {                                                                     \
      _Pragma("unroll")                                                            \
      for (int nj = 0; nj < 4; ++nj)                                               \
        bfr[nj] = ldsfrag(BSLOT, wc*64 + nj*16 + lrow, pslot);                     \
    }                                                                              \
    _Pragma("unroll")                                                              \
    for (int mi = 0; mi < 4; ++mi)                                                 \
      afr[mi] = ldsfrag(ASLOT, wr*128 + ((MIOFF)+mi)*16 + lrow, pslot);            \
    STAGE_STMT;                                                                    \
    asm volatile("s_waitcnt lgkmcnt(0)" ::: "memory");                             \
    asm volatile("s_barrier" ::: "memory");                                        \
    _Pragma("unroll")                                                              \
    for (int mi = 0; mi < 4; ++mi)                                                 \
      _Pragma("unroll")                                                            \
      for (int nj = 0; nj < 4; ++nj)                                               \
        acc[(MIOFF)+mi][nj] = __builtin_amdgcn_mfma_f32_16x16x32_bf16(             \
            afr[mi], bfr[nj], acc[(MIOFF)+mi][nj], 0, 0, 0);                       \
    if (VMW) asm volatile("s_waitcnt vmcnt(6)" ::: "memory");                      \
    asm volatile("s_barrier" ::: "memory");                                        \
  } while (0)

  for (int nc = 0; nc < NCHUNKS; ++nc) {
    #pragma unroll
    for (int kt = 0; kt < 4; ++kt) {
      const int par  = kt & 1;
      const int npar = par ^ 1;
      // Stage ledger: ph0 completes tile T+1 (A ks1); ph1-3 issue tile T+2's
      // {B ks0, A ks0, B ks1}. vmcnt(6) at ph3 => tile T+1 fully landed.
      const int ncA1 = (kt < 3) ? nc : ((nc + 1) & (NCHUNKS - 1));  // T+1's chunk
      const int kA1  = ((kt + 1) & 3) * 64 + 32;
      const int ncT2 = (kt < 2) ? nc : ((nc + 1) & (NCHUNKS - 1));  // T+2's chunk
      const int kT2  = ((kt + 2) & 3) * 64;
      const int offA1 = (nbase + ncA1 * 256) * DDIM + kA1;
      const int offA2 = (nbase + ncT2 * 256) * DDIM + kT2;

      PHASE(1, LDSB(par,0), LDSA(par,0), 0, STAGE_A(LDSA(npar,1), offA1), 0);
      PHASE(0, LDSB(par,0), LDSA(par,0), 4, STAGE_B(LDSB(par,0), kT2),    0);
      PHASE(1, LDSB(par,1), LDSA(par,1), 0, STAGE_A(LDSA(par,0), offA2),  0);
      PHASE(0, LDSB(par,1), LDSA(par,1), 4, STAGE_B(LDSB(par,1), kT2+32), 1);
    }
    // fold this n-chunk's C tile into running column max; reset acc
    #pragma unroll
    for (int nj = 0; nj < 4; ++nj) {
      float v = cm[nj];
      #pragma unroll
      for (int mi = 0; mi < 8; ++mi) {
        v = fmaxf(fmaxf(fmaxf(fmaxf(v, acc[mi][nj][0]), acc[mi][nj][1]),
                        acc[mi][nj][2]), acc[mi][nj][3]);
        acc[mi][nj] = (f32x4){0.0f, 0.0f, 0.0f, 0.0f};
      }
      cm[nj] = v;
    }
  }
  #undef PHASE

  // ---- Epilogue: drain DMA, reduce max across lanes/waves, write partials
  asm volatile("s_waitcnt vmcnt(0)" ::: "memory");
  asm volatile("s_barrier" ::: "memory");
  float* cmax = (float*)lds;   // [2][256]
  #pragma unroll
  for (int nj = 0; nj < 4; ++nj) {
    cm[nj] = fmaxf(cm[nj], __shfl_xor(cm[nj], 16, 64));
    cm[nj] = fmaxf(cm[nj], __shfl_xor(cm[nj], 32, 64));
  }
  if (lane < 16) {
    #pragma unroll
    for (int nj = 0; nj < 4; ++nj)
      cmax[wr * 256 + wc * 64 + nj * 16 + lane] = cm[nj];
  }
  __syncthreads();
  if (t < 256) {
    float v = fmaxf(cmax[t], cmax[256 + t]);
    partials[((size_t)sp * BATCH + bb) * MROWS + m0 + t] = v;
  }
}

// ---------------- Kernel 3a: per-batch loss ----------------
__global__ void __launch_bounds__(256) batch_loss(
    const float* __restrict__ partials, const float* __restrict__ y,
    float* __restrict__ bloss) {
  __shared__ float red[4];
  const int b = blockIdx.x;
  const int t = threadIdx.x;
  const int lane = t & 63;
  const int w = t >> 6;
  float s = 0.0f;
  for (int m = t; m < MROWS; m += 256) {
    float v = partials[(size_t)b * MROWS + m];
    #pragma unroll
    for (int sp = 1; sp < NSPLIT; ++sp)
      v = fmaxf(v, partials[((size_t)sp * BATCH + b) * MROWS + m]);
    s += v;
  }
  #pragma unroll
  for (int o = 32; o >= 1; o >>= 1) s += __shfl_xor(s, o, 64);
  if (lane == 0) red[w] = s;
  __syncthreads();
  if (t == 0) {
    float sum = red[0] + red[1] + red[2] + red[3];
    float mean = sum / (float)MROWS;
    float yb = y[b];
    float d = mean - yb;
    bloss[b] = d * d;   // Y_SCALE == 1.0
  }
}

// ---------------- Kernel 3b: combine per-batch losses ----------------
__global__ void __launch_bounds__(64) final_sum(
    const float* __restrict__ bloss, float* __restrict__ out) {
  const int t = threadIdx.x;
  float v = (t < BATCH) ? bloss[t] : 0.0f;
  #pragma unroll
  for (int o = 32; o >= 1; o >>= 1) v += __shfl_xor(v, o, 64);
  if (t == 0) out[0] = v;
}

extern "C" void kernel_launch(void* const* d_in, const int* in_sizes, int n_in,
                              void* d_out, int out_size, void* d_ws, size_t ws_size,
                              hipStream_t stream) {
  const float* x1 = (const float*)d_in[0];
  const float* x2 = (const float*)d_in[1];
  const float* y  = (const float*)d_in[2];
  float* out = (float*)d_out;

  unsigned short* aBF = (unsigned short*)d_ws;
  unsigned short* bBF = aBF + (size_t)BATCH * NROWS * DDIM;
  float* partials = (float*)(bBF + (size_t)BATCH * MROWS * DDIM);
  float* bloss = partials + (size_t)NSPLIT * BATCH * MROWS;

  const int totRows = BATCH * (NROWS + MROWS);
  norm_cast<<<(totRows + 3) / 4, 256, 0, stream>>>(x1, x2, aBF, bBF);
  maxsim_gemm8<<<BATCH * 8 * NSPLIT, 512, 0, stream>>>(aBF, bBF, partials);
  batch_loss<<<BATCH, 256, 0, stream>>>(partials, y, bloss);
  final_sum<<<1, 64, 0, stream>>>(bloss, out);
}

// Round 14
// 61.253 us; speedup vs baseline: 1.9976x; 1.4032x over previous
//
#include <hip/hip_runtime.h>
#include <hip/hip_bf16.h>
#include <cstdint>
#include <cstddef>

#define BATCH 16
#define NROWS 4096
#define MROWS 2048
#define DDIM  256
#define NSPLIT 2
#define NCHUNKS 8            // (NROWS/NSPLIT)/256

typedef __attribute__((ext_vector_type(8)))  int   i32x8;
typedef __attribute__((ext_vector_type(16))) float f32x16;

// ---------------- Kernel 1: row L2-normalize + fp8(e4m3) cast ----------------
__global__ void __launch_bounds__(256) norm_cast(
    const float* __restrict__ x1, const float* __restrict__ x2,
    unsigned char* __restrict__ aout, unsigned char* __restrict__ bout) {
  const int wid  = threadIdx.x >> 6;
  const int lane = threadIdx.x & 63;
  const long long row = (long long)blockIdx.x * 4 + wid;
  const long long R1 = (long long)BATCH * NROWS;
  const long long R2 = (long long)BATCH * MROWS;
  if (row >= R1 + R2) return;
  const float* src; unsigned char* dst;
  if (row < R1) { src = x1 + row * DDIM; dst = aout + row * DDIM; }
  else { long long r2 = row - R1; src = x2 + r2 * DDIM; dst = bout + r2 * DDIM; }
  float4 v = ((const float4*)src)[lane];
  float ss = v.x*v.x + v.y*v.y + v.z*v.z + v.w*v.w;
  #pragma unroll
  for (int o = 32; o >= 1; o >>= 1) ss += __shfl_xor(ss, o, 64);
  float sc = 1.0f / fmaxf(sqrtf(ss), 1e-12f);
  // HW fp32->fp8 e4m3 (OCP on gfx950), RNE, handles denormals.
  int r = __builtin_amdgcn_cvt_pk_fp8_f32(v.x * sc, v.y * sc, 0, false);
  r = __builtin_amdgcn_cvt_pk_fp8_f32(v.z * sc, v.w * sc, r, true);
  ((unsigned int*)dst)[lane] = (unsigned int)r;
}

// ---------------- Kernel 2: MX-fp8 256x256 fused GEMM + column-max ----------------
typedef __attribute__((address_space(1))) const void gas_t;
typedef __attribute__((address_space(3))) void las_t;
#define GLL16(g, l) __builtin_amdgcn_global_load_lds((gas_t*)(g), (las_t*)(l), 16, 0, 0)

// LDS: 2 A slots + 2 B slots of [256 rows][64 B] fp8 = 16 KB each; 64 KB total.
#define LDSA(P) (lds + ((P) << 14))
#define LDSB(P) (lds + 32768 + ((P) << 14))

// Read a 32x32x64 A/B fragment: lane holds row (l&31), k-bytes (l>>5)*32..+31.
// LDS k-slots are XOR-swizzled by row bits 1-2 (matches staging pre-swizzle).
static __device__ __forceinline__ i32x8 frag8(const char* slot, int row, int lane) {
  const int rb = (lane >> 1) & 3;
  const int ks = lane >> 5;
  const char* base = slot + row * 64;
  uint4 u0 = *(const uint4*)(base + ((((ks << 1) | 0) ^ rb) << 4));
  uint4 u1 = *(const uint4*)(base + ((((ks << 1) | 1) ^ rb) << 4));
  i32x8 r;
  r[0] = u0.x; r[1] = u0.y; r[2] = u0.z; r[3] = u0.w;
  r[4] = u1.x; r[5] = u1.y; r[6] = u1.z; r[7] = u1.w;
  return r;
}

__global__ void __launch_bounds__(512, 1) maxsim_fp8(
    const unsigned char* __restrict__ A,    // [BATCH][NROWS][DDIM] fp8
    const unsigned char* __restrict__ Bm,   // [BATCH][MROWS][DDIM] fp8
    float* __restrict__ partials)           // [NSPLIT][BATCH][MROWS]
{
  __shared__ __align__(16) char lds[65536];

  const int t = threadIdx.x;
  const int lane = t & 63;
  const int w = t >> 6;
  const int wr = w >> 2;     // n-half (wave owns 128 rows)
  const int wc = w & 3;      // m-quarter (wave owns 64 cols)
  const int l31 = lane & 31;

  // XCD-aware bijective swizzle: 256 blocks, XCD k owns batches {2k,2k+1}.
  const int hw = blockIdx.x;
  const int logical = (hw & 7) * 32 + (hw >> 3);
  const int mt = logical & 7;
  const int grp = logical >> 3;
  const int sp = grp & 1;
  const int bb = grp >> 1;

  const int m0 = mt * 256;
  const int nbase = sp * (NROWS / NSPLIT);

  const unsigned char* Aba = A  + (size_t)bb * NROWS * DDIM;
  const unsigned char* Bba = Bm + ((size_t)bb * MROWS + m0) * DDIM;

  // Staging: slot [256 rows][64 B]; 512 thr x 2 x 16B = 16 KB.
  // chunk c = w*2+i covers rows c*16 + (lane>>2); 16B k-slot kq = lane&3,
  // source pre-swizzled: sphys = kq ^ ((row>>1)&3) = kq ^ ((lane>>3)&3).
  const int r0 = (w * 2 + 0) * 16 + (lane >> 2);
  const int r1 = (w * 2 + 1) * 16 + (lane >> 2);
  const int sph = (((lane & 3) ^ ((lane >> 3) & 3)) << 4);   // bytes
  const unsigned char* sA0 = Aba + (size_t)r0 * DDIM + sph;
  const unsigned char* sA1 = Aba + (size_t)r1 * DDIM + sph;
  const unsigned char* sB0 = Bba + (size_t)r0 * DDIM + sph;
  const unsigned char* sB1 = Bba + (size_t)r1 * DDIM + sph;
  const int l0 = (w * 2 + 0) * 1024 + lane * 16;   // slot-relative LDS dest
  const int l1 = (w * 2 + 1) * 1024 + lane * 16;

  #define STAGE_A(SLOT, OFF) do { \
    GLL16(sA0 + (OFF), (SLOT) + l0); GLL16(sA1 + (OFF), (SLOT) + l1); } while (0)
  #define STAGE_B(SLOT, OFF) do { \
    GLL16(sB0 + (OFF), (SLOT) + l0); GLL16(sB1 + (OFF), (SLOT) + l1); } while (0)

  f32x16 acc[4][2] = {};
  const f32x16 z16 = {};
  i32x8 af[4], bf[2];
  float cm[2] = {-INFINITY, -INFINITY};

  // ---- Prologue: stage T0 -> slot0, T1 -> slot1 (8 wave-loads).
  STAGE_A(LDSA(0), (size_t)nbase * DDIM + 0);
  STAGE_B(LDSB(0), 0);
  STAGE_A(LDSA(1), (size_t)nbase * DDIM + 64);
  STAGE_B(LDSB(1), 64);
  asm volatile("s_waitcnt vmcnt(4)" ::: "memory");   // T0 landed; T1 in flight
  asm volatile("s_barrier" ::: "memory");

  // Single phase per K-tile(64): 12 ds_reads; lgkm+bar (slot p free);
  // stage T+2 into slot p; 8 MFMA(32x32x64); vmcnt(4) (T+1 landed); bar.
  for (int nc = 0; nc < NCHUNKS; ++nc) {
    #pragma unroll
    for (int kt = 0; kt < 4; ++kt) {
      const int p = kt & 1;
      char* sa = LDSA(p);
      char* sb = LDSB(p);
      // T+2 source (junk-wrap to chunk 0 on last 2 global tiles; never read)
      const int kk2 = (kt + 2) & 3;
      const int nc2 = (kt < 2) ? nc : ((nc + 1) & (NCHUNKS - 1));
      const size_t offA2 = ((size_t)nbase + nc2 * 256) * DDIM + kk2 * 64;
      const int offB2 = kk2 * 64;

      #pragma unroll
      for (int nj = 0; nj < 2; ++nj)
        bf[nj] = frag8(sb, wc * 64 + nj * 32 + l31, lane);
      #pragma unroll
      for (int mi = 0; mi < 4; ++mi)
        af[mi] = frag8(sa, wr * 128 + mi * 32 + l31, lane);
      asm volatile("s_waitcnt lgkmcnt(0)" ::: "memory");
      asm volatile("s_barrier" ::: "memory");   // all waves done reading slot p
      STAGE_A(sa, offA2);
      STAGE_B(sb, offB2);
      #pragma unroll
      for (int mi = 0; mi < 4; ++mi)
        #pragma unroll
        for (int nj = 0; nj < 2; ++nj)
          acc[mi][nj] = __builtin_amdgcn_mfma_scale_f32_32x32x64_f8f6f4(
              af[mi], bf[nj], acc[mi][nj], 0, 0,
              0, 0x7F7F7F7F, 0, 0x7F7F7F7F);   // E8M0 0x7F = scale 1.0
      asm volatile("s_waitcnt vmcnt(4)" ::: "memory");   // T+1 fully landed
      asm volatile("s_barrier" ::: "memory");
    }
    // fold chunk's C into running column max; reset acc.
    // C/D 32x32: col = lane&31, rows spread over 16 regs + (lane>>5).
    #pragma unroll
    for (int nj = 0; nj < 2; ++nj) {
      float v = cm[nj];
      #pragma unroll
      for (int mi = 0; mi < 4; ++mi) {
        #pragma unroll
        for (int r = 0; r < 16; ++r) v = fmaxf(v, acc[mi][nj][r]);
        acc[mi][nj] = z16;
      }
      cm[nj] = v;
    }
  }

  // ---- Epilogue: drain DMA; reduce across lane halves + waves; write partials.
  asm volatile("s_waitcnt vmcnt(0)" ::: "memory");
  asm volatile("s_barrier" ::: "memory");
  #pragma unroll
  for (int nj = 0; nj < 2; ++nj)
    cm[nj] = fmaxf(cm[nj], __shfl_xor(cm[nj], 32, 64));
  float* cmax = (float*)lds;   // [2][256]
  if (lane < 32) {
    cmax[wr * 256 + wc * 64 + l31]      = cm[0];
    cmax[wr * 256 + wc * 64 + 32 + l31] = cm[1];
  }
  __syncthreads();
  if (t < 256) {
    float v = fmaxf(cmax[t], cmax[256 + t]);
    partials[((size_t)sp * BATCH + bb) * MROWS + m0 + t] = v;
  }
}

// ---------------- Kernel 3a: per-batch loss ----------------
__global__ void __launch_bounds__(256) batch_loss(
    const float* __restrict__ partials, const float* __restrict__ y,
    float* __restrict__ bloss) {
  __shared__ float red[4];
  const int b = blockIdx.x;
  const int t = threadIdx.x;
  const int lane = t & 63;
  const int w = t >> 6;
  float s = 0.0f;
  for (int m = t; m < MROWS; m += 256) {
    float v = partials[(size_t)b * MROWS + m];
    #pragma unroll
    for (int sp = 1; sp < NSPLIT; ++sp)
      v = fmaxf(v, partials[((size_t)sp * BATCH + b) * MROWS + m]);
    s += v;
  }
  #pragma unroll
  for (int o = 32; o >= 1; o >>= 1) s += __shfl_xor(s, o, 64);
  if (lane == 0) red[w] = s;
  __syncthreads();
  if (t == 0) {
    float sum = red[0] + red[1] + red[2] + red[3];
    float mean = sum / (float)MROWS;
    float yb = y[b];
    float d = mean - yb;
    bloss[b] = d * d;   // Y_SCALE == 1.0
  }
}

// ---------------- Kernel 3b: combine per-batch losses ----------------
__global__ void __launch_bounds__(64) final_sum(
    const float* __restrict__ bloss, float* __restrict__ out) {
  const int t = threadIdx.x;
  float v = (t < BATCH) ? bloss[t] : 0.0f;
  #pragma unroll
  for (int o = 32; o >= 1; o >>= 1) v += __shfl_xor(v, o, 64);
  if (t == 0) out[0] = v;
}

extern "C" void kernel_launch(void* const* d_in, const int* in_sizes, int n_in,
                              void* d_out, int out_size, void* d_ws, size_t ws_size,
                              hipStream_t stream) {
  const float* x1 = (const float*)d_in[0];
  const float* x2 = (const float*)d_in[1];
  const float* y  = (const float*)d_in[2];
  float* out = (float*)d_out;

  unsigned char* aF8 = (unsigned char*)d_ws;                          // 16 MB
  unsigned char* bF8 = aF8 + (size_t)BATCH * NROWS * DDIM;            // 8 MB
  float* partials = (float*)(bF8 + (size_t)BATCH * MROWS * DDIM);     // 256 KB
  float* bloss = partials + (size_t)NSPLIT * BATCH * MROWS;

  const int totRows = BATCH * (NROWS + MROWS);
  norm_cast<<<(totRows + 3) / 4, 256, 0, stream>>>(x1, x2, aF8, bF8);
  maxsim_fp8<<<BATCH * 8 * NSPLIT, 512, 0, stream>>>(aF8, bF8, partials);
  batch_loss<<<BATCH, 256, 0, stream>>>(partials, y, bloss);
  final_sum<<<1, 64, 0, stream>>>(bloss, out);
}

// Round 15
// 54.158 us; speedup vs baseline: 2.2593x; 1.1310x over previous
//
#include <hip/hip_runtime.h>
#include <hip/hip_bf16.h>
#include <cstdint>
#include <cstddef>

#define BATCH 16
#define NROWS 4096
#define MROWS 2048
#define DDIM  256
#define NSPLIT 2
#define NCHUNKS 8            // (NROWS/NSPLIT)/256

typedef __attribute__((ext_vector_type(8)))  int   i32x8;
typedef __attribute__((ext_vector_type(16))) float f32x16;

// ---------------- Kernel 1: row L2-normalize + fp8(e4m3) cast ----------------
__global__ void __launch_bounds__(256) norm_cast(
    const float* __restrict__ x1, const float* __restrict__ x2,
    unsigned char* __restrict__ aout, unsigned char* __restrict__ bout) {
  const int wid  = threadIdx.x >> 6;
  const int lane = threadIdx.x & 63;
  const long long row = (long long)blockIdx.x * 4 + wid;
  const long long R1 = (long long)BATCH * NROWS;
  const long long R2 = (long long)BATCH * MROWS;
  if (row >= R1 + R2) return;
  const float* src; unsigned char* dst;
  if (row < R1) { src = x1 + row * DDIM; dst = aout + row * DDIM; }
  else { long long r2 = row - R1; src = x2 + r2 * DDIM; dst = bout + r2 * DDIM; }
  float4 v = ((const float4*)src)[lane];
  float ss = v.x*v.x + v.y*v.y + v.z*v.z + v.w*v.w;
  #pragma unroll
  for (int o = 32; o >= 1; o >>= 1) ss += __shfl_xor(ss, o, 64);
  float sc = 1.0f / fmaxf(sqrtf(ss), 1e-12f);
  // HW fp32->fp8 e4m3 (OCP on gfx950), RNE.
  int r = __builtin_amdgcn_cvt_pk_fp8_f32(v.x * sc, v.y * sc, 0, false);
  r = __builtin_amdgcn_cvt_pk_fp8_f32(v.z * sc, v.w * sc, r, true);
  ((unsigned int*)dst)[lane] = (unsigned int)r;
}

// ---------------- Kernel 2: MX-fp8 GEMM, B-resident LDS + 4-slot A-ring ----------------
typedef __attribute__((address_space(1))) const void gas_t;
typedef __attribute__((address_space(3))) void las_t;
#define GLL16(g, l) __builtin_amdgcn_global_lds((gas_t*)(g), (las_t*)(l), 16, 0, 0)
#undef GLL16
#define GLL16(g, l) __builtin_amdgcn_global_load_lds((gas_t*)(g), (las_t*)(l), 16, 0, 0)

// LDS: 4 A ring slots [256 rows][64 B] = 64 KB; 4 resident B slots = 64 KB.
#define LDSA(S) (lds + ((S) << 14))
#define LDSB(S) (lds + 65536 + ((S) << 14))

// 32x32x64 fragment read: lane holds row (l&31), k-bytes (l>>5)*32..+31.
// k-slots XOR-swizzled by row bits 1-2 (matches staging pre-swizzle).
static __device__ __forceinline__ i32x8 frag8(const char* slot, int row, int lane) {
  const int rb = (lane >> 1) & 3;
  const int ks = lane >> 5;
  const char* base = slot + row * 64;
  uint4 u0 = *(const uint4*)(base + ((((ks << 1) | 0) ^ rb) << 4));
  uint4 u1 = *(const uint4*)(base + ((((ks << 1) | 1) ^ rb) << 4));
  i32x8 r;
  r[0] = u0.x; r[1] = u0.y; r[2] = u0.z; r[3] = u0.w;
  r[4] = u1.x; r[5] = u1.y; r[6] = u1.z; r[7] = u1.w;
  return r;
}

__global__ void __launch_bounds__(512, 1) maxsim_fp8(
    const unsigned char* __restrict__ A,    // [BATCH][NROWS][DDIM] fp8
    const unsigned char* __restrict__ Bm,   // [BATCH][MROWS][DDIM] fp8
    float* __restrict__ partials)           // [NSPLIT][BATCH][MROWS]
{
  __shared__ __align__(16) char lds[131072];

  const int t = threadIdx.x;
  const int lane = t & 63;
  const int w = t >> 6;
  const int wr = w >> 2;     // n-half (wave owns 128 rows)
  const int wc = w & 3;      // m-quarter (wave owns 64 cols)
  const int l31 = lane & 31;

  // XCD-aware bijective swizzle: 256 blocks, XCD k owns batches {2k,2k+1}.
  const int hw = blockIdx.x;
  const int logical = (hw & 7) * 32 + (hw >> 3);
  const int mt = logical & 7;
  const int grp = logical >> 3;
  const int sp = grp & 1;
  const int bb = grp >> 1;

  const int m0 = mt * 256;
  const int nbase = sp * (NROWS / NSPLIT);

  const unsigned char* Aba = A  + (size_t)bb * NROWS * DDIM;
  const unsigned char* Bba = Bm + ((size_t)bb * MROWS + m0) * DDIM;

  // Staging: slot [256 rows][64 B]; 512 thr x 2 x 16B = 16 KB per slot-fill.
  // chunk c = w*2+i covers rows c*16 + (lane>>2); 16B k-slot kq = lane&3,
  // source pre-swizzled: sphys = kq ^ ((row>>1)&3) = kq ^ ((lane>>3)&3).
  const int r0 = (w * 2 + 0) * 16 + (lane >> 2);
  const int r1 = (w * 2 + 1) * 16 + (lane >> 2);
  const int sph = (((lane & 3) ^ ((lane >> 3) & 3)) << 4);   // bytes
  const unsigned char* sA0 = Aba + (size_t)r0 * DDIM + sph;
  const unsigned char* sA1 = Aba + (size_t)r1 * DDIM + sph;
  const unsigned char* sB0 = Bba + (size_t)r0 * DDIM + sph;
  const unsigned char* sB1 = Bba + (size_t)r1 * DDIM + sph;
  const int l0 = (w * 2 + 0) * 1024 + lane * 16;   // slot-relative LDS dest
  const int l1 = (w * 2 + 1) * 1024 + lane * 16;

  #define STAGE_A(SLOT, OFF) do { \
    GLL16(sA0 + (OFF), (SLOT) + l0); GLL16(sA1 + (OFF), (SLOT) + l1); } while (0)
  #define STAGE_B(SLOT, OFF) do { \
    GLL16(sB0 + (OFF), (SLOT) + l0); GLL16(sB1 + (OFF), (SLOT) + l1); } while (0)

  f32x16 acc[4][2] = {};
  const f32x16 z16 = {};
  i32x8 af[4], bf[2];
  float cm[2] = {-INFINITY, -INFINITY};

  // ---- Prologue: A tiles 0,1 -> ring slots 0,1; ALL of B (4 slots, resident).
  STAGE_A(LDSA(0), (size_t)nbase * DDIM + 0);
  STAGE_B(LDSB(0), 0);
  STAGE_B(LDSB(1), 64);
  STAGE_B(LDSB(2), 128);
  STAGE_B(LDSB(3), 192);
  STAGE_A(LDSA(1), (size_t)nbase * DDIM + 64);
  asm volatile("s_waitcnt vmcnt(8)" ::: "memory");   // A0+B0 (oldest 4) landed
  asm volatile("s_barrier" ::: "memory");

  // Per K-tile(64): 12 ds_reads; stage A for T+2 into ring slot (kt+2)&3
  // (WAR distance = 2 barriers); 8 MFMA (compiler-progressive lgkm waits);
  // vmcnt(2) => T+1's A landed; ONE barrier.
  for (int nc = 0; nc < NCHUNKS; ++nc) {
    #pragma unroll
    for (int kt = 0; kt < 4; ++kt) {
      const char* sa = LDSA(kt);
      const char* sb = LDSB(kt);
      const int s2 = (kt + 2) & 3;
      const int nc2 = (kt < 2) ? nc : ((nc + 1) & (NCHUNKS - 1));  // junk-wrap tail
      const size_t offA2 = ((size_t)nbase + nc2 * 256) * DDIM + s2 * 64;

      #pragma unroll
      for (int nj = 0; nj < 2; ++nj)
        bf[nj] = frag8(sb, wc * 64 + nj * 32 + l31, lane);
      #pragma unroll
      for (int mi = 0; mi < 4; ++mi)
        af[mi] = frag8(sa, wr * 128 + mi * 32 + l31, lane);
      STAGE_A(LDSA(s2), offA2);
      #pragma unroll
      for (int mi = 0; mi < 4; ++mi)
        #pragma unroll
        for (int nj = 0; nj < 2; ++nj)
          acc[mi][nj] = __builtin_amdgcn_mfma_scale_f32_32x32x64_f8f6f4(
              af[mi], bf[nj], acc[mi][nj], 0, 0,
              0, 0x7F7F7F7F, 0, 0x7F7F7F7F);   // E8M0 0x7F = scale 1.0
      asm volatile("s_waitcnt vmcnt(2)" ::: "memory");   // T+1's A landed
      asm volatile("s_barrier" ::: "memory");
    }
    // fold chunk's C into running column max; reset acc.
    // C/D 32x32: col = lane&31, 16 regs spread rows, + (lane>>5) offset.
    #pragma unroll
    for (int nj = 0; nj < 2; ++nj) {
      float v = cm[nj];
      #pragma unroll
      for (int mi = 0; mi < 4; ++mi) {
        #pragma unroll
        for (int r = 0; r < 16; ++r) v = fmaxf(v, acc[mi][nj][r]);
        acc[mi][nj] = z16;
      }
      cm[nj] = v;
    }
  }

  // ---- Epilogue: drain DMA; reduce across lane halves + waves; write partials.
  asm volatile("s_waitcnt vmcnt(0)" ::: "memory");
  asm volatile("s_barrier" ::: "memory");
  #pragma unroll
  for (int nj = 0; nj < 2; ++nj)
    cm[nj] = fmaxf(cm[nj], __shfl_xor(cm[nj], 32, 64));
  float* cmax = (float*)lds;   // [2][256]
  if (lane < 32) {
    cmax[wr * 256 + wc * 64 + l31]      = cm[0];
    cmax[wr * 256 + wc * 64 + 32 + l31] = cm[1];
  }
  __syncthreads();
  if (t < 256) {
    float v = fmaxf(cmax[t], cmax[256 + t]);
    partials[((size_t)sp * BATCH + bb) * MROWS + m0 + t] = v;
  }
}

// ---------------- Kernel 3a: per-batch loss ----------------
__global__ void __launch_bounds__(256) batch_loss(
    const float* __restrict__ partials, const float* __restrict__ y,
    float* __restrict__ bloss) {
  __shared__ float red[4];
  const int b = blockIdx.x;
  const int t = threadIdx.x;
  const int lane = t & 63;
  const int w = t >> 6;
  float s = 0.0f;
  for (int m = t; m < MROWS; m += 256) {
    float v = partials[(size_t)b * MROWS + m];
    #pragma unroll
    for (int sp = 1; sp < NSPLIT; ++sp)
      v = fmaxf(v, partials[((size_t)sp * BATCH + b) * MROWS + m]);
    s += v;
  }
  #pragma unroll
  for (int o = 32; o >= 1; o >>= 1) s += __shfl_xor(s, o, 64);
  if (lane == 0) red[w] = s;
  __syncthreads();
  if (t == 0) {
    float sum = red[0] + red[1] + red[2] + red[3];
    float mean = sum / (float)MROWS;
    float yb = y[b];
    float d = mean - yb;
    bloss[b] = d * d;   // Y_SCALE == 1.0
  }
}

// ---------------- Kernel 3b: combine per-batch losses ----------------
__global__ void __launch_bounds__(64) final_sum(
    const float* __restrict__ bloss, float* __restrict__ out) {
  const int t = threadIdx.x;
  float v = (t < BATCH) ? bloss[t] : 0.0f;
  #pragma unroll
  for (int o = 32; o >= 1; o >>= 1) v += __shfl_xor(v, o, 64);
  if (t == 0) out[0] = v;
}

extern "C" void kernel_launch(void* const* d_in, const int* in_sizes, int n_in,
                              void* d_out, int out_size, void* d_ws, size_t ws_size,
                              hipStream_t stream) {
  const float* x1 = (const float*)d_in[0];
  const float* x2 = (const float*)d_in[1];
  const float* y  = (const float*)d_in[2];
  float* out = (float*)d_out;

  unsigned char* aF8 = (unsigned char*)d_ws;                          // 16 MB
  unsigned char* bF8 = aF8 + (size_t)BATCH * NROWS * DDIM;            // 8 MB
  float* partials = (float*)(bF8 + (size_t)BATCH * MROWS * DDIM);     // 256 KB
  float* bloss = partials + (size_t)NSPLIT * BATCH * MROWS;

  const int totRows = BATCH * (NROWS + MROWS);
  norm_cast<<<(totRows + 3) / 4, 256, 0, stream>>>(x1, x2, aF8, bF8);
  maxsim_fp8<<<BATCH * 8 * NSPLIT, 512, 0, stream>>>(aF8, bF8, partials);
  batch_loss<<<BATCH, 256, 0, stream>>>(partials, y, bloss);
  final_sum<<<1, 64, 0, stream>>>(bloss, out);
}